// Round 3
// baseline (661.223 us; speedup 1.0000x reference)
//
#include <hip/hip_runtime.h>

#define Bb 8
#define Tt 4096
#define Hh 1024
#define Mm 2048
#define Kk 32
#define Rr 1024

// ---------------------------------------------------------------------------
// Stage 1: weighted[q,d] = sum_k scores[q,k] * values[q,k,d]
// One block per mention q, 256 threads, float4. Memory-bound: 256 MB read.
// ---------------------------------------------------------------------------
__global__ __launch_bounds__(256) void k_weighted(
    const float* __restrict__ scores,   // [M,K]
    const float* __restrict__ values,   // [M,K,R]
    float* __restrict__ weighted) {     // [M,R]
  int q = blockIdx.x;
  int t = threadIdx.x;
  __shared__ float s[Kk];
  if (t < Kk) s[t] = scores[q * Kk + t];
  __syncthreads();
  const float4* vv = (const float4*)(values + (size_t)q * Kk * Rr);
  float4 acc = make_float4(0.f, 0.f, 0.f, 0.f);
#pragma unroll 16
  for (int k = 0; k < Kk; ++k) {
    float4 v = vv[k * (Rr / 4) + t];
    float sk = s[k];
    acc.x += sk * v.x; acc.y += sk * v.y; acc.z += sk * v.z; acc.w += sk * v.w;
  }
  ((float4*)(weighted + (size_t)q * Rr))[t] = acc;
}

// ---------------------------------------------------------------------------
// Stage 2: proj = (weighted @ W + b) * mask   [M,H]
// fp32 vector GEMM (no fp32-input MFMA on CDNA4). A in registers (8 rows per
// thread, loaded from L2; in-wave same-line dups coalesce), B LDS-staged
// (0.25 B/FLOP < 0.33 LDS machine balance). Software-pipelined: Bs double
// buffer (ONE barrier per k-step) + unroll-2 with two named A reg sets so all
// indexing is compile-time (no scratch). Prefetch of step s+1 issues before
// compute of step s -> ~512 VALU cyc covers L2 latency even at 1 wave/SIMD.
// ---------------------------------------------------------------------------
#define BM 128
#define BN 64
#define BKk 8
#define NSTEP (Rr / BKk)   // 128

#define PREF_A(dst, k0)                                                   \
  _Pragma("unroll") for (int i = 0; i < 8; ++i) {                         \
    *(float4*)&dst[i][0] = *(const float4*)(Arow + (size_t)i * Rr + (k0));\
    *(float4*)&dst[i][4] = *(const float4*)(Arow + (size_t)i * Rr + (k0) + 4);\
  }

#define LOAD_B(bv, k0)                                                    \
  if (tid < 128) bv = *(const float4*)(Wm + (size_t)((k0) + br) * Hh + bn + bc4 * 4);

#define STORE_B(buf, bv)                                                  \
  if (tid < 128) *(float4*)(&Bs[buf][br][bc4 * 4]) = bv;

#define COMPUTE(a, buf)                                                   \
  _Pragma("unroll") for (int kk = 0; kk < BKk; ++kk) {                    \
    float4 b = *(const float4*)(&Bs[buf][kk][tx * 4]);                    \
    _Pragma("unroll") for (int i = 0; i < 8; ++i) {                       \
      float av = a[i][kk];                                                \
      acc[i][0] += av * b.x; acc[i][1] += av * b.y;                       \
      acc[i][2] += av * b.z; acc[i][3] += av * b.w;                       \
    }                                                                     \
  }

__global__ __launch_bounds__(256, 1) void k_gemm(
    const float* __restrict__ A,       // [M,R] weighted
    const float* __restrict__ Wm,      // [R,H]
    const float* __restrict__ bias,    // [H]
    const int* __restrict__ mask,      // [M]
    float* __restrict__ C) {           // [M,H]
  __shared__ float Bs[2][BKk][BN];
  int tid = threadIdx.x;
  int tx = tid & 15;        // n: 4 cols at bn + tx*4
  int ty = tid >> 4;        // m: 8 rows at bm + ty*8
  int bn = blockIdx.x * BN;
  int bm = blockIdx.y * BM;
  int br = tid >> 4, bc4 = tid & 15;  // B stage mapping (tid < 128)
  const float* Arow = A + (size_t)(bm + ty * 8) * Rr;

  float acc[8][4];
#pragma unroll
  for (int i = 0; i < 8; ++i)
#pragma unroll
    for (int j = 0; j < 4; ++j) acc[i][j] = 0.f;

  float aE[8][8], aO[8][8];
  float4 bv;

  // prologue: step 0 operands
  PREF_A(aE, 0)
  LOAD_B(bv, 0)
  STORE_B(0, bv)
  __syncthreads();

  for (int s = 0; s < NSTEP - 2; s += 2) {
    // even step s: compute(aE, Bs[0]); prefetch step s+1 -> aO, Bs[1]
    PREF_A(aO, (s + 1) * BKk)
    LOAD_B(bv, (s + 1) * BKk)
    COMPUTE(aE, 0)
    STORE_B(1, bv)
    __syncthreads();
    // odd step s+1: compute(aO, Bs[1]); prefetch step s+2 -> aE, Bs[0]
    PREF_A(aE, (s + 2) * BKk)
    LOAD_B(bv, (s + 2) * BKk)
    COMPUTE(aO, 1)
    STORE_B(0, bv)
    __syncthreads();
  }
  // step NSTEP-2 (even): prefetch final step only
  PREF_A(aO, (NSTEP - 1) * BKk)
  LOAD_B(bv, (NSTEP - 1) * BKk)
  COMPUTE(aE, 0)
  STORE_B(1, bv)
  __syncthreads();
  // step NSTEP-1 (odd, final)
  COMPUTE(aO, 1)

  float4 bias4 = *(const float4*)(bias + bn + tx * 4);
#pragma unroll
  for (int i = 0; i < 8; ++i) {
    int row = bm + ty * 8 + i;
    float mk = (float)mask[row];
    float4 o;
    o.x = (acc[i][0] + bias4.x) * mk;
    o.y = (acc[i][1] + bias4.y) * mk;
    o.z = (acc[i][2] + bias4.z) * mk;
    o.w = (acc[i][3] + bias4.w) * mk;
    *(float4*)(C + (size_t)row * Hh + bn + tx * 4) = o;
  }
}

// ---------------------------------------------------------------------------
// Stage 3: per-row linked list of mentions (handles duplicate (b,s) pairs).
// ---------------------------------------------------------------------------
__global__ void k_init_head(int* __restrict__ head) {
  int i = blockIdx.x * 256 + threadIdx.x;
  if (i < Bb * Tt) head[i] = -1;
}

__global__ void k_link(const int* __restrict__ bpos, const int* __restrict__ spos,
                       const int* __restrict__ mask, int* __restrict__ head,
                       int* __restrict__ nxt) {
  int m = blockIdx.x * 256 + threadIdx.x;
  if (m < Mm && mask[m] != 0) {
    int row = bpos[m] * Tt + spos[m];
    nxt[m] = atomicExch(&head[row], m);  // device-scope, duplicates chain
  }
}

// ---------------------------------------------------------------------------
// Stage 4: fused scatter-add + LayerNorm. One block per (b,t) row.
// Two-pass mean/var (matches mean((x-mean)^2) numerics).
// ---------------------------------------------------------------------------
__global__ __launch_bounds__(256) void k_ln(
    const float* __restrict__ x,       // [B,T,H] encoded_input
    const float* __restrict__ proj,    // [M,H]
    const int* __restrict__ head, const int* __restrict__ nxt,
    const float* __restrict__ scale, const float* __restrict__ bias,
    float* __restrict__ out) {
  int row = blockIdx.x;
  int t = threadIdx.x;
  float4 v = ((const float4*)(x + (size_t)row * Hh))[t];
  for (int m = head[row]; m >= 0; m = nxt[m]) {
    float4 p = ((const float4*)(proj + (size_t)m * Hh))[t];
    v.x += p.x; v.y += p.y; v.z += p.z; v.w += p.w;
  }
  __shared__ float sbuf[4];
  int lane = t & 63, wave = t >> 6;

  float sum = v.x + v.y + v.z + v.w;
#pragma unroll
  for (int off = 32; off; off >>= 1) sum += __shfl_down(sum, off);
  if (lane == 0) sbuf[wave] = sum;
  __syncthreads();
  float mean = (sbuf[0] + sbuf[1] + sbuf[2] + sbuf[3]) * (1.0f / Hh);
  __syncthreads();

  float cx = v.x - mean, cy = v.y - mean, cz = v.z - mean, cw = v.w - mean;
  float ssq = cx * cx + cy * cy + cz * cz + cw * cw;
#pragma unroll
  for (int off = 32; off; off >>= 1) ssq += __shfl_down(ssq, off);
  if (lane == 0) sbuf[wave] = ssq;
  __syncthreads();
  float var = (sbuf[0] + sbuf[1] + sbuf[2] + sbuf[3]) * (1.0f / Hh);
  float inv = 1.0f / sqrtf(var + 1e-12f);

  float4 sc = ((const float4*)scale)[t];
  float4 bi = ((const float4*)bias)[t];
  float4 o;
  o.x = cx * inv * sc.x + bi.x;
  o.y = cy * inv * sc.y + bi.y;
  o.z = cz * inv * sc.z + bi.z;
  o.w = cw * inv * sc.w + bi.w;
  ((float4*)(out + (size_t)row * Hh))[t] = o;
}

// ---------------------------------------------------------------------------
extern "C" void kernel_launch(void* const* d_in, const int* in_sizes, int n_in,
                              void* d_out, int out_size, void* d_ws, size_t ws_size,
                              hipStream_t stream) {
  const float* enc      = (const float*)d_in[0];
  const float* rvals    = (const float*)d_in[1];
  const float* rscores  = (const float*)d_in[2];
  const float* Wm       = (const float*)d_in[3];
  const float* bias     = (const float*)d_in[4];
  const float* ln_scale = (const float*)d_in[5];
  const float* ln_bias  = (const float*)d_in[6];
  const int* bpos = (const int*)d_in[7];
  const int* spos = (const int*)d_in[8];
  // d_in[9] = mention_end_positions: unused by reference
  const int* mask = (const int*)d_in[10];
  float* out = (float*)d_out;

  char* ws = (char*)d_ws;
  float* weighted = (float*)ws;                                   // 8 MB
  float* proj = (float*)(ws + (size_t)Mm * Rr * 4);               // 8 MB
  int* head = (int*)(ws + (size_t)Mm * Rr * 4 + (size_t)Mm * Hh * 4); // 128 KB
  int* nxt = (int*)((char*)head + (size_t)Bb * Tt * 4);           // 8 KB

  hipLaunchKernelGGL(k_weighted, dim3(Mm), dim3(256), 0, stream,
                     rscores, rvals, weighted);
  hipLaunchKernelGGL(k_gemm, dim3(Hh / BN, Mm / BM), dim3(256), 0, stream,
                     weighted, Wm, bias, mask, proj);
  hipLaunchKernelGGL(k_init_head, dim3((Bb * Tt + 255) / 256), dim3(256), 0, stream,
                     head);
  hipLaunchKernelGGL(k_link, dim3((Mm + 255) / 256), dim3(256), 0, stream,
                     bpos, spos, mask, head, nxt);
  hipLaunchKernelGGL(k_ln, dim3(Bb * Tt), dim3(256), 0, stream,
                     enc, proj, head, nxt, ln_scale, ln_bias, out);
}